// Round 1
// 109.622 us; speedup vs baseline: 1.0189x; 1.0189x over previous
//
#include <hip/hip_runtime.h>
#include <hip/hip_fp16.h>

#define P_DIM 1024
#define H_DIM 256
#define L_DIM 16384
#define DT 0.001f
#define TWOPI 6.283185307179586f
#define INV2PI 0.15915494309189535f
#define WSCALE 4096.0f
#define INV_WSCALE (1.0f / 4096.0f)
#define BM 128
#define BN 128
#define BK 64
#define NT 256
#define LDB 72   // padded Bs leading dim (halves): linear layout, write addrs fold to immediates

typedef _Float16 f16x8 __attribute__((ext_vector_type(8)));
typedef float f32x4 __attribute__((ext_vector_type(4)));

#define GPTR(p) (const __attribute__((address_space(1))) unsigned*)(p)
#define LPTR(p) (__attribute__((address_space(3))) unsigned*)(p)

union H2U { __half2 h; unsigned u; };

__device__ __forceinline__ float2 cmulf(float2 a, float2 b) {
    return make_float2(a.x * b.x - a.y * b.y, a.x * b.y + a.y * b.x);
}

// ---------- prep: W2[h][p] = C[h,p]*scale(p)*B[p,h] * 4096, fp16 pair ----------
__global__ __launch_bounds__(256)
void prep_kernel(const float* __restrict__ Ag, const float* __restrict__ Bg,
                 const float* __restrict__ Cg, __half* __restrict__ W2) {
    __shared__ float2 Bt[64][33];   // [p][h] tile, padded
    __shared__ float2 sc[64];
    const int t  = threadIdx.x;
    const int p0 = (blockIdx.x & 15) << 6;   // 16 p-blocks of 64
    const int h0 = (blockIdx.x >> 4) << 5;   // 8 h-blocks of 32

    if (t < 64) {
        float2 a = ((const float2*)Ag)[p0 + t];
        float er = __expf(a.x * DT);
        float s, c; __sincosf(a.y * DT, &s, &c);
        float nr = er * c - 1.f, ni = er * s;
        float inv = 1.f / (a.x * a.x + a.y * a.y);
        sc[t] = make_float2((nr * a.x + ni * a.y) * inv, (ni * a.x - nr * a.y) * inv);
    }
    #pragma unroll
    for (int i = 0; i < 8; ++i) {           // B: (p,h) layout, h fastest -> coalesced
        int idx = i * 256 + t, p = idx >> 5, h = idx & 31;
        Bt[p][h] = ((const float2*)Bg)[(size_t)(p0 + p) * H_DIM + h0 + h];
    }
    __syncthreads();
    #pragma unroll
    for (int i = 0; i < 8; ++i) {           // C: (h,p) layout, p fastest -> coalesced
        int idx = i * 256 + t, h = idx >> 6, p = idx & 63;
        float2 cc = ((const float2*)Cg)[(size_t)(h0 + h) * P_DIM + p0 + p];
        float2 s2 = sc[p], b = Bt[p][h];
        float2 tv = cmulf(cc, s2);
        float wr = (tv.x * b.x - tv.y * b.y) * WSCALE;
        float wi = (tv.x * b.y + tv.y * b.x) * WSCALE;
        ((__half2*)W2)[(size_t)(h0 + h) * P_DIM + p0 + p] =
            __float22half2_rn(make_float2(wr, wi));
    }
}

// ---------- main: fused GEMM + V-gen, double-buffered, 1 barrier/chunk ----------
__global__ __launch_bounds__(NT, 2)
void vand_mfma_kernel(const float* __restrict__ Ag,
                      const _Float16* __restrict__ W2,
                      float* __restrict__ out) {
    __shared__ __attribute__((aligned(16))) _Float16 As[2][BM * BK];   // 2x16KB, XOR-swizzled (DMA)
    __shared__ __attribute__((aligned(16))) _Float16 Bs[2][BN * LDB];  // 2x18KB, padded linear (VALU-written)
    __shared__ float2 Atab[P_DIM];                                     // 8KB: A_bar per p

    const int tid  = threadIdx.x;
    const int lane = tid & 63;
    const int w    = tid >> 6;
    const int wm   = w & 1, wn = w >> 1;
    const int m0   = blockIdx.y * BM;
    const int nb   = blockIdx.x * BN;
    const int lb   = blockIdx.x * (BN / 2);

    const float2* Ag2 = (const float2*)Ag;

    // ---- A_bar table: 4 p's per thread, once per block (amortized over 32 chunks) ----
    #pragma unroll
    for (int i = 0; i < 4; ++i) {
        int p = tid + i * 256;
        float2 a = Ag2[p];
        float e = __expf(a.x * DT);
        float s, c; __sincosf(a.y * DT, &s, &c);
        Atab[p] = make_float2(e * c, e * s);
    }

    f32x4 acc[4][4];
    #pragma unroll
    for (int mt = 0; mt < 4; ++mt)
        #pragma unroll
        for (int nt = 0; nt < 4; ++nt)
            acc[mt][nt] = (f32x4){0.f, 0.f, 0.f, 0.f};

    // V-gen mapping: 1 p x 8 l per thread (anchor + 7-step recurrence)
    const int pl    = tid & 31;            // p within 32-wide chunk
    const int lg    = tid >> 5;            // l-group 0..7
    const float l0f = (float)(lb + lg * 8);
    const int bpbase = lg * 16 * LDB + 2 * pl;   // half-index of row 16*lg, col 2*pl

    // DMA mapping (per wave: 32 rows of A)
    const int goff = (lane >> 3) * 2048 + (((lane & 7) ^ (lane >> 3)) << 3);
    const _Float16* gwbase = W2 + (size_t)(m0 + (w << 5)) * 2048;
    const int ldsoff = (w << 5) * 64;

    _Float16* Acur = &As[0][0]; _Float16* Bcur = &Bs[0][0];
    _Float16* Anxt = &As[1][0]; _Float16* Bnxt = &Bs[1][0];

#define DMA_CHUNK(K0, DST)                                                        \
    {                                                                             \
        const _Float16* gw = gwbase + (K0) + goff;                                \
        _Float16* lB = (DST) + ldsoff;                                            \
        _Pragma("unroll")                                                         \
        for (int r = 0; r < 4; ++r)                                               \
            __builtin_amdgcn_global_load_lds(GPTR(gw + r * 8 * 2048),             \
                                             LPTR(lB + r * 8 * 64), 16, 0, 0);    \
    }

    // per chunk/thread: 1 glb ld + 1 LDS tab ld + {exp,sincos,rint} + 7 cmul +
    // 16 cvt_pk + 16 immediate-offset ds_write_b32  (was ~103 VALU + 12 trans)
#define VGEN_CHUNK(K0, DST)                                                       \
    {                                                                             \
        const int pg = ((K0) >> 1) + pl;                                          \
        float2 a  = Ag2[pg];                                                      \
        float2 ab = Atab[pg];                                                     \
        float cx = a.x * DT, cy = a.y * (DT * INV2PI);                            \
        float mg = __expf(cx * l0f);                                              \
        float x  = cy * l0f; x -= rintf(x);                                       \
        float s, c; __sincosf(x * TWOPI, &s, &c);                                 \
        float2 v = make_float2(mg * c, mg * s);                                   \
        _Float16* bp = (DST) + bpbase;                                            \
        _Pragma("unroll")                                                         \
        for (int j = 0; j < 8; ++j) {                                             \
            H2U u0, u1;                                                           \
            u0.h = __float22half2_rn(make_float2(v.x, -v.y));                     \
            u1.h = __float22half2_rn(make_float2(v.y, v.x));                      \
            *(unsigned*)(bp + j * 2 * LDB)       = u0.u;                          \
            *(unsigned*)(bp + j * 2 * LDB + LDB) = u1.u;                          \
            if (j < 7) v = cmulf(v, ab);                                          \
        }                                                                         \
    }

    __syncthreads();                 // Atab visible to all threads
    // prologue: chunk 0
    DMA_CHUNK(0, Acur)
    VGEN_CHUNK(0, Bcur)
    __syncthreads();

    for (int kk = 0; kk < 32; ++kk) {
        if (kk < 31) {
            const int k1 = (kk + 1) * BK;
            DMA_CHUNK(k1, Anxt)
            VGEN_CHUNK(k1, Bnxt)
        }
        #pragma unroll
        for (int ks = 0; ks < 2; ++ks) {
            f16x8 af[4], bf[4];
            const int g = ks * 4 + (lane >> 4);
            #pragma unroll
            for (int t = 0; t < 4; ++t) {
                int m = wm * 64 + t * 16 + (lane & 15);
                af[t] = *(const f16x8*)(Acur + m * 64 + ((g ^ (m & 7)) << 3));
                int n = wn * 64 + t * 16 + (lane & 15);
                bf[t] = *(const f16x8*)(Bcur + n * LDB + (g << 3));
            }
            #pragma unroll
            for (int mt = 0; mt < 4; ++mt)
                #pragma unroll
                for (int nt = 0; nt < 4; ++nt)
                    acc[mt][nt] = __builtin_amdgcn_mfma_f32_16x16x32_f16(
                        af[mt], bf[nt], acc[mt][nt], 0, 0, 0);
        }
        __syncthreads();
        _Float16* tA = Acur; Acur = Anxt; Anxt = tA;
        _Float16* tB = Bcur; Bcur = Bnxt; Bnxt = tB;
    }

    // epilogue: C/D layout col=lane&15, row=(lane>>4)*4+r
    #pragma unroll
    for (int mt = 0; mt < 4; ++mt) {
        #pragma unroll
        for (int nt = 0; nt < 4; ++nt) {
            int h = m0 + wm * 64 + mt * 16 + ((lane >> 4) << 2);
            int n = nb + wn * 64 + nt * 16 + (lane & 15);
            #pragma unroll
            for (int r = 0; r < 4; ++r)
                out[(size_t)(h + r) * 32768 + n] = acc[mt][nt][r] * INV_WSCALE;
        }
    }
#undef DMA_CHUNK
#undef VGEN_CHUNK
}

extern "C" void kernel_launch(void* const* d_in, const int* in_sizes, int n_in,
                              void* d_out, int out_size, void* d_ws, size_t ws_size,
                              hipStream_t stream) {
    const float* A = (const float*)d_in[0];   // (P, 2)
    const float* B = (const float*)d_in[1];   // (P, H, 2)
    const float* C = (const float*)d_in[2];   // (H, P, 2)
    float* out = (float*)d_out;               // (H, L, 2)
    __half* W2 = (__half*)d_ws;               // (256, 2048) fp16, 1 MB

    prep_kernel<<<dim3(128), dim3(256), 0, stream>>>(A, B, C, W2);
    vand_mfma_kernel<<<dim3(L_DIM * 2 / BN, H_DIM / BM), dim3(NT), 0, stream>>>(
        A, (const _Float16*)W2, out);
}

// Round 2
// 107.907 us; speedup vs baseline: 1.0351x; 1.0159x over previous
//
#include <hip/hip_runtime.h>
#include <hip/hip_fp16.h>

#define P_DIM 1024
#define H_DIM 256
#define L_DIM 16384
#define DT 0.001f
#define TWOPI 6.283185307179586f
#define INV2PI 0.15915494309189535f
#define WSCALE 4096.0f
#define INV_WSCALE (1.0f / 4096.0f)
#define BM 128
#define BN 128
#define BK 64
#define NT 256

typedef _Float16 f16x8 __attribute__((ext_vector_type(8)));
typedef float f32x4 __attribute__((ext_vector_type(4)));

#define GPTR(p) (const __attribute__((address_space(1))) unsigned*)(p)
#define LPTR(p) (__attribute__((address_space(3))) unsigned*)(p)

union H2U { __half2 h; unsigned u; };

__device__ __forceinline__ float2 cmulf(float2 a, float2 b) {
    return make_float2(a.x * b.x - a.y * b.y, a.x * b.y + a.y * b.x);
}

// ---------- prep: W2[h][p] = C[h,p]*scale(p)*B[p,h] * 4096, fp16 pair ----------
__global__ __launch_bounds__(256)
void prep_kernel(const float* __restrict__ Ag, const float* __restrict__ Bg,
                 const float* __restrict__ Cg, __half* __restrict__ W2) {
    __shared__ float2 Bt[64][33];   // [p][h] tile, padded
    __shared__ float2 sc[64];
    const int t  = threadIdx.x;
    const int p0 = (blockIdx.x & 15) << 6;   // 16 p-blocks of 64
    const int h0 = (blockIdx.x >> 4) << 5;   // 8 h-blocks of 32

    if (t < 64) {
        float2 a = ((const float2*)Ag)[p0 + t];
        float er = __expf(a.x * DT);
        float s, c; __sincosf(a.y * DT, &s, &c);
        float nr = er * c - 1.f, ni = er * s;
        float inv = 1.f / (a.x * a.x + a.y * a.y);
        sc[t] = make_float2((nr * a.x + ni * a.y) * inv, (ni * a.x - nr * a.y) * inv);
    }
    #pragma unroll
    for (int i = 0; i < 8; ++i) {           // B: (p,h) layout, h fastest -> coalesced
        int idx = i * 256 + t, p = idx >> 5, h = idx & 31;
        Bt[p][h] = ((const float2*)Bg)[(size_t)(p0 + p) * H_DIM + h0 + h];
    }
    __syncthreads();
    #pragma unroll
    for (int i = 0; i < 8; ++i) {           // C: (h,p) layout, p fastest -> coalesced
        int idx = i * 256 + t, h = idx >> 6, p = idx & 63;
        float2 cc = ((const float2*)Cg)[(size_t)(h0 + h) * P_DIM + p0 + p];
        float2 s2 = sc[p], b = Bt[p][h];
        float2 tv = cmulf(cc, s2);
        float wr = (tv.x * b.x - tv.y * b.y) * WSCALE;
        float wi = (tv.x * b.y + tv.y * b.x) * WSCALE;
        ((__half2*)W2)[(size_t)(h0 + h) * P_DIM + p0 + p] =
            __float22half2_rn(make_float2(wr, wi));
    }
}

// ---------- main: fused GEMM + V-gen, counted-vmcnt pipeline (T4) ----------
__global__ __launch_bounds__(NT, 2)
void vand_mfma_kernel(const float* __restrict__ Ag,
                      const _Float16* __restrict__ W2,
                      float* __restrict__ out) {
    __shared__ __attribute__((aligned(16))) _Float16 As[2][BM * BK];  // 2x16KB, XOR (DMA)
    __shared__ __attribute__((aligned(16))) _Float16 Bs[2][BN * BK];  // 2x16KB, XOR (VALU)
    __shared__ float4 Atab[P_DIM];   // 16KB: (abar_re, abar_im, cx, cy) per p
    // total 80KB -> exactly 2 blocks/CU

    const int tid  = threadIdx.x;
    const int lane = tid & 63;
    const int w    = tid >> 6;
    const int wm   = w & 1, wn = w >> 1;
    const int m0   = blockIdx.y * BM;
    const int nb   = blockIdx.x * BN;
    const int lb   = blockIdx.x * (BN / 2);

    const float2* Ag2 = (const float2*)Ag;

    // ---- Atab: A_bar and anchor coeffs per p, once per block ----
    #pragma unroll
    for (int i = 0; i < 4; ++i) {
        int p = tid + i * 256;
        float2 a = Ag2[p];
        float e = __expf(a.x * DT);
        float s, c; __sincosf(a.y * DT, &s, &c);
        Atab[p] = make_float4(e * c, e * s, a.x * DT, a.y * (DT * INV2PI));
    }

    f32x4 acc[4][4];
    #pragma unroll
    for (int mt = 0; mt < 4; ++mt)
        #pragma unroll
        for (int nt = 0; nt < 4; ++nt)
            acc[mt][nt] = (f32x4){0.f, 0.f, 0.f, 0.f};

    // V-gen mapping: 1 p x 8 l per thread (anchor + 7-step recurrence)
    const int pl    = tid & 31;                  // p within 32-wide chunk
    const int lg    = tid >> 5;                  // l-group 0..7
    const float l0f = (float)(lb + lg * 8);
    const int cq3   = (pl >> 2) << 3;            // XOR group, pre-shifted
    const int cs    = (2 * pl) & 7;              // in-group half offset (even)
    const int vbase = lg * 1024 + cs;            // halves: row 16*lg, col 2*pl

    // DMA mapping (per wave: 32 rows of A), XOR pre-applied on global source
    const int goff = (lane >> 3) * 2048 + (((lane & 7) ^ (lane >> 3)) << 3);
    const _Float16* gwbase = W2 + (size_t)(m0 + (w << 5)) * 2048;
    const int ldsoff = (w << 5) * 64;

    _Float16* Acur = &As[0][0]; _Float16* Bcur = &Bs[0][0];
    _Float16* Anxt = &As[1][0]; _Float16* Bnxt = &Bs[1][0];

#define DMA_CHUNK(K0, DST)                                                        \
    {                                                                             \
        const _Float16* gw = gwbase + (K0) + goff;                                \
        _Float16* lB = (DST) + ldsoff;                                            \
        _Pragma("unroll")                                                         \
        for (int r = 0; r < 4; ++r)                                               \
            __builtin_amdgcn_global_load_lds(GPTR(gw + r * 8 * 2048),             \
                                             LPTR(lB + r * 8 * 64), 16, 0, 0);    \
    }

    // per chunk/thread: 1 ds_read_b128 (Atab) + {exp,sincos,rint} + 7 cmul +
    // 16 cvt + 16 ds_write_b32 (XOR addrs, ~2 VALU each). No global loads.
#define VGEN_CHUNK(K0, DST)                                                       \
    {                                                                             \
        const int pg = ((K0) >> 1) + pl;                                          \
        float4 t4 = Atab[pg];                                                     \
        float mg = __expf(t4.z * l0f);                                            \
        float x  = t4.w * l0f; x -= rintf(x);                                     \
        float s, c; __sincosf(x * TWOPI, &s, &c);                                 \
        float2 v  = make_float2(mg * c, mg * s);                                  \
        float2 ab = make_float2(t4.x, t4.y);                                      \
        _Pragma("unroll")                                                         \
        for (int j = 0; j < 8; ++j) {                                             \
            H2U u0, u1;                                                           \
            u0.h = __float22half2_rn(make_float2(v.x, -v.y));                     \
            u1.h = __float22half2_rn(make_float2(v.y, v.x));                      \
            int e0 = vbase + j * 128 + (cq3 ^ (((2 * j) & 7) << 3));              \
            int e1 = vbase + j * 128 + 64 + (cq3 ^ (((2 * j + 1) & 7) << 3));     \
            *(unsigned*)((DST) + e0) = u0.u;                                      \
            *(unsigned*)((DST) + e1) = u1.u;                                      \
            if (j < 7) v = cmulf(v, ab);                                          \
        }                                                                         \
    }

    // prologue
    DMA_CHUNK(0, Acur)
    __syncthreads();                 // Atab visible; drains DMA(0) (once, ok)
    VGEN_CHUNK(0, Bcur)

    for (int kk = 0; kk < 32; ++kk) {
        if (kk < 31) {
            const int k1 = (kk + 1) * BK;
            DMA_CHUNK(k1, Anxt)
            VGEN_CHUNK(k1, Bnxt)
            // own DMA(kk) done (4 newer loads stay in flight), own VGEN writes done
            asm volatile("s_waitcnt vmcnt(4) lgkmcnt(0)" ::: "memory");
        } else {
            asm volatile("s_waitcnt vmcnt(0) lgkmcnt(0)" ::: "memory");
        }
        __builtin_amdgcn_sched_barrier(0);
        __builtin_amdgcn_s_barrier();        // all waves: As[kk]+Bs[kk] ready
        __builtin_amdgcn_sched_barrier(0);

        __builtin_amdgcn_s_setprio(1);
        #pragma unroll
        for (int ks = 0; ks < 2; ++ks) {
            f16x8 af[4], bf[4];
            const int g = ks * 4 + (lane >> 4);
            #pragma unroll
            for (int t = 0; t < 4; ++t) {
                int m = wm * 64 + t * 16 + (lane & 15);
                af[t] = *(const f16x8*)(Acur + m * 64 + ((g ^ (m & 7)) << 3));
                int n = wn * 64 + t * 16 + (lane & 15);
                bf[t] = *(const f16x8*)(Bcur + n * 64 + ((g ^ (n & 7)) << 3));
            }
            #pragma unroll
            for (int mt = 0; mt < 4; ++mt)
                #pragma unroll
                for (int nt = 0; nt < 4; ++nt)
                    acc[mt][nt] = __builtin_amdgcn_mfma_f32_16x16x32_f16(
                        af[mt], bf[nt], acc[mt][nt], 0, 0, 0);
        }
        __builtin_amdgcn_s_setprio(0);
        __builtin_amdgcn_sched_barrier(0);
        __builtin_amdgcn_s_barrier();        // protect buffers for next overwrite
        __builtin_amdgcn_sched_barrier(0);

        _Float16* tA = Acur; Acur = Anxt; Anxt = tA;
        _Float16* tB = Bcur; Bcur = Bnxt; Bnxt = tB;
    }

    // epilogue: C/D layout col=lane&15, row=(lane>>4)*4+r
    #pragma unroll
    for (int mt = 0; mt < 4; ++mt) {
        #pragma unroll
        for (int nt = 0; nt < 4; ++nt) {
            int h = m0 + wm * 64 + mt * 16 + ((lane >> 4) << 2);
            int n = nb + wn * 64 + nt * 16 + (lane & 15);
            #pragma unroll
            for (int r = 0; r < 4; ++r)
                out[(size_t)(h + r) * 32768 + n] = acc[mt][nt][r] * INV_WSCALE;
        }
    }
#undef DMA_CHUNK
#undef VGEN_CHUNK
}

extern "C" void kernel_launch(void* const* d_in, const int* in_sizes, int n_in,
                              void* d_out, int out_size, void* d_ws, size_t ws_size,
                              hipStream_t stream) {
    const float* A = (const float*)d_in[0];   // (P, 2)
    const float* B = (const float*)d_in[1];   // (P, H, 2)
    const float* C = (const float*)d_in[2];   // (H, P, 2)
    float* out = (float*)d_out;               // (H, L, 2)
    __half* W2 = (__half*)d_ws;               // (256, 2048) fp16, 1 MB

    prep_kernel<<<dim3(128), dim3(256), 0, stream>>>(A, B, C, W2);
    vand_mfma_kernel<<<dim3(L_DIM * 2 / BN, H_DIM / BM), dim3(NT), 0, stream>>>(
        A, (const _Float16*)W2, out);
}